// Round 1
// baseline (6291.339 us; speedup 1.0000x reference)
//
#include <hip/hip_runtime.h>
#include <math.h>

// SchNet forward, MI355X fp32 baseline.
// Key idea: the continuous filter W(d) = ssp(rbf(d)@w1+b1)@w2+b2 depends only on
// the scalar edge distance d. Tabulate it on a 2048-point grid over [0, DMAX]
// (per layer, 2048x600 table) and linearly interpolate per edge; apply the cosine
// cutoff C exactly. Interp error ~4e-8 (|W''| <~ 20, h=0.0042) vs 1.4e-3 budget.
// This removes the E x H x H GEMM (64% of reference FLOPs).

#define N_ATOMS 10000
#define E_EDGES 64000
#define B_MOLS  128
#define H_DIM   600
#define G_DIM   50
#define L_LAYERS 6
#define M_TAB   2048
#define DMAX    8.67f          // max possible d = sqrt(75) = 8.66025
#define LOG2C   0.69314718056f

#define BM 64
#define BN 64
#define BK 16

__device__ __forceinline__ float sspf(float x) {
    // softplus(x) - log(2), numerically stable
    return fmaxf(x, 0.0f) + log1pf(expf(-fabsf(x))) - LOG2C;
}

// ---------------------------------------------------------------- GEMM
// out[Ma,Nc] = op(A[Ma,K](lda) @ W[K,Nc] + bias), op in {id, ssp}, optional +=
template<bool BIAS, bool ACT, bool ACCUM>
__global__ __launch_bounds__(256)
void gemm_k(const float* __restrict__ A, int lda,
            const float* __restrict__ W,
            const float* __restrict__ bias,
            float* __restrict__ out,
            int Ma, int K, int Nc)
{
    __shared__ __align__(16) float As[BK][BM];   // transposed: As[k][m]
    __shared__ __align__(16) float Bs[BK][BN];   // Bs[k][n]

    const int tid = threadIdx.x;
    const int tx = tid & 15, ty = tid >> 4;
    const int m0 = blockIdx.y * BM, n0 = blockIdx.x * BN;

    // A-tile load mapping: 64 rows x 16 k, one float4 per thread along K
    const int ar = tid >> 2;          // 0..63
    const int ac = (tid & 3) << 2;    // 0,4,8,12
    // B-tile load mapping: 16 k x 64 n, one float4 per thread along N
    const int br = tid >> 4;          // 0..15
    const int bc = (tid & 15) << 2;   // 0..60

    float acc[4][4] = {};

    for (int k0 = 0; k0 < K; k0 += BK) {
        // ---- stage A tile (transposed into LDS)
        {
            int row = m0 + ar;
            int col = k0 + ac;
            float4 v = make_float4(0.f, 0.f, 0.f, 0.f);
            if (row < Ma) {
                const float* ap = A + (size_t)row * lda + col;
                if (col + 3 < K) {
                    v = *(const float4*)ap;
                } else {
                    if (col + 0 < K) v.x = ap[0];
                    if (col + 1 < K) v.y = ap[1];
                    if (col + 2 < K) v.z = ap[2];
                    if (col + 3 < K) v.w = ap[3];
                }
            }
            As[ac + 0][ar] = v.x;
            As[ac + 1][ar] = v.y;
            As[ac + 2][ar] = v.z;
            As[ac + 3][ar] = v.w;
        }
        // ---- stage B tile
        {
            int row = k0 + br;
            int col = n0 + bc;
            float4 v = make_float4(0.f, 0.f, 0.f, 0.f);
            if (row < K) {
                const float* wp = W + (size_t)row * Nc + col;
                if (col + 3 < Nc) {
                    v = *(const float4*)wp;
                } else {
                    if (col + 0 < Nc) v.x = wp[0];
                    if (col + 1 < Nc) v.y = wp[1];
                    if (col + 2 < Nc) v.z = wp[2];
                    if (col + 3 < Nc) v.w = wp[3];
                }
            }
            *(float4*)&Bs[br][bc] = v;
        }
        __syncthreads();

        #pragma unroll
        for (int kk = 0; kk < BK; ++kk) {
            float4 a4 = *(const float4*)&As[kk][ty << 2];
            float4 b4 = *(const float4*)&Bs[kk][tx << 2];
            float av[4] = {a4.x, a4.y, a4.z, a4.w};
            float bv[4] = {b4.x, b4.y, b4.z, b4.w};
            #pragma unroll
            for (int i = 0; i < 4; ++i)
                #pragma unroll
                for (int j = 0; j < 4; ++j)
                    acc[i][j] = fmaf(av[i], bv[j], acc[i][j]);
        }
        __syncthreads();
    }

    // ---- epilogue
    #pragma unroll
    for (int i = 0; i < 4; ++i) {
        int row = m0 + (ty << 2) + i;
        if (row >= Ma) continue;
        int col = n0 + (tx << 2);
        float* op = out + (size_t)row * Nc + col;
        if (col + 3 < Nc) {
            float vals[4];
            #pragma unroll
            for (int j = 0; j < 4; ++j) {
                float v = acc[i][j];
                if constexpr (BIAS) v += bias[col + j];
                if constexpr (ACT)  v = sspf(v);
                vals[j] = v;
            }
            float4 o;
            if constexpr (ACCUM) {
                float4 prev = *(const float4*)op;
                o = make_float4(vals[0] + prev.x, vals[1] + prev.y,
                                vals[2] + prev.z, vals[3] + prev.w);
            } else {
                o = make_float4(vals[0], vals[1], vals[2], vals[3]);
            }
            *(float4*)op = o;
        } else {
            #pragma unroll
            for (int j = 0; j < 4; ++j) {
                int cj = col + j;
                if (cj < Nc) {
                    float v = acc[i][j];
                    if constexpr (BIAS) v += bias[cj];
                    if constexpr (ACT)  v = sspf(v);
                    if constexpr (ACCUM) v += op[j];
                    op[j] = v;
                }
            }
        }
    }
}

// ---------------------------------------------------------------- helpers
__global__ __launch_bounds__(256)
void init_h_k(const int* __restrict__ z, const float* __restrict__ emb,
              float* __restrict__ h)
{
    int t = blockIdx.x * 256 + threadIdx.x;
    const int QH = H_DIM / 4;
    if (t >= N_ATOMS * QH) return;
    int i = t / QH;
    int q = (t - i * QH) << 2;
    *(float4*)(h + (size_t)i * H_DIM + q) =
        *(const float4*)(emb + (size_t)z[i] * H_DIM + q);
}

__global__ __launch_bounds__(256)
void edge_geom_k(const float* __restrict__ pos, const int* __restrict__ src,
                 const int* __restrict__ dst, float* __restrict__ de,
                 float* __restrict__ ce)
{
    int e = blockIdx.x * 256 + threadIdx.x;
    if (e >= E_EDGES) return;
    int s = src[e], d0 = dst[e];
    float dx = pos[s * 3 + 0] - pos[d0 * 3 + 0];
    float dy = pos[s * 3 + 1] - pos[d0 * 3 + 1];
    float dz = pos[s * 3 + 2] - pos[d0 * 3 + 2];
    float dist = sqrtf(dx * dx + dy * dy + dz * dz + 1e-12f);
    de[e] = dist;
    ce[e] = 0.5f * (cosf(dist * 0.31415926535f) + 1.0f);   // pi/CUTOFF
}

// rbf table [M_TAB, 64] (padded to 64 cols so GEMM lda keeps 16B alignment)
__global__ __launch_bounds__(256)
void rbf_tab_k(float* __restrict__ rtab)
{
    int t = blockIdx.x * 256 + threadIdx.x;
    if (t >= M_TAB * 64) return;
    int i = t >> 6, g = t & 63;
    float v = 0.0f;
    if (g < G_DIM) {
        float dg  = (float)i * (DMAX / (float)(M_TAB - 1));
        float off = (float)g * (10.0f / 49.0f);
        float x = dg - off;
        const float coeff = -0.5f * (49.0f / 10.0f) * (49.0f / 10.0f);
        v = expf(coeff * x * x);
    }
    rtab[t] = v;
}

// per-edge: W = lerp(Wtab, d) * C; agg[dst] += y[src] * W
__global__ __launch_bounds__(256)
void scatter_k(const float* __restrict__ y, const float* __restrict__ wt,
               const float* __restrict__ de, const float* __restrict__ ce,
               const int* __restrict__ src, const int* __restrict__ dst,
               float* __restrict__ agg)
{
    int t = blockIdx.x * 256 + threadIdx.x;
    const int QH = H_DIM / 4;
    if (t >= E_EDGES * QH) return;
    int e = t / QH;
    int q = (t - e * QH) << 2;
    int s = src[e], d0 = dst[e];
    float dd = de[e], cc = ce[e];
    float u = dd * ((float)(M_TAB - 1) / DMAX);
    u = fminf(fmaxf(u, 0.0f), (float)(M_TAB - 1) - 0.001f);
    int i0 = (int)u;
    float f = u - (float)i0;
    const float4 w0 = *(const float4*)(wt + (size_t)i0 * H_DIM + q);
    const float4 w1 = *(const float4*)(wt + (size_t)(i0 + 1) * H_DIM + q);
    const float4 yv = *(const float4*)(y + (size_t)s * H_DIM + q);
    float* ap = agg + (size_t)d0 * H_DIM + q;
    atomicAdd(ap + 0, yv.x * (w0.x + f * (w1.x - w0.x)) * cc);
    atomicAdd(ap + 1, yv.y * (w0.y + f * (w1.y - w0.y)) * cc);
    atomicAdd(ap + 2, yv.z * (w0.z + f * (w1.z - w0.z)) * cc);
    atomicAdd(ap + 3, yv.w * (w0.w + f * (w1.w - w0.w)) * cc);
}

__global__ __launch_bounds__(256)
void pool_sum_k(const float* __restrict__ h, const int* __restrict__ batch,
                float* __restrict__ sums)
{
    int t = blockIdx.x * 256 + threadIdx.x;
    const int QH = H_DIM / 4;
    if (t >= N_ATOMS * QH) return;
    int i = t / QH;
    int q = (t - i * QH) << 2;
    int b = batch[i];
    const float4 hv = *(const float4*)(h + (size_t)i * H_DIM + q);
    float* sp = sums + (size_t)b * H_DIM + q;
    atomicAdd(sp + 0, hv.x);
    atomicAdd(sp + 1, hv.y);
    atomicAdd(sp + 2, hv.z);
    atomicAdd(sp + 3, hv.w);
}

__global__ __launch_bounds__(256)
void cnt_k(const int* __restrict__ batch, float* __restrict__ cnt)
{
    int i = blockIdx.x * 256 + threadIdx.x;
    if (i >= N_ATOMS) return;
    atomicAdd(&cnt[batch[i]], 1.0f);
}

__global__ __launch_bounds__(256)
void pool_div_k(float* __restrict__ sums, const float* __restrict__ cnt)
{
    int t = blockIdx.x * 256 + threadIdx.x;
    if (t >= B_MOLS * H_DIM) return;
    sums[t] /= fmaxf(cnt[t / H_DIM], 1.0f);
}

// ---------------------------------------------------------------- launch
extern "C" void kernel_launch(void* const* d_in, const int* in_sizes, int n_in,
                              void* d_out, int out_size, void* d_ws, size_t ws_size,
                              hipStream_t stream)
{
    const int*   z      = (const int*)  d_in[0];
    const float* pos    = (const float*)d_in[1];
    const int*   batch  = (const int*)  d_in[2];
    const int*   eidx   = (const int*)  d_in[3];
    const float* emb    = (const float*)d_in[4];
    const float* mlp_w1 = (const float*)d_in[5];
    const float* mlp_b1 = (const float*)d_in[6];
    const float* mlp_w2 = (const float*)d_in[7];
    const float* mlp_b2 = (const float*)d_in[8];
    const float* lin1_w = (const float*)d_in[9];
    const float* lin2_w = (const float*)d_in[10];
    const float* lin2_b = (const float*)d_in[11];
    const float* intw   = (const float*)d_in[12];
    const float* intb   = (const float*)d_in[13];
    const float* poolw  = (const float*)d_in[14];
    const float* poolb  = (const float*)d_in[15];

    float* ws   = (float*)d_ws;
    float* h    = ws;                       // N*H = 6,000,000
    float* y    = ws + 6000000;             // N*H
    float* agg  = ws + 12000000;            // N*H
    float* ttab = ws + 18000000;            // M_TAB*H = 1,228,800
    float* wtab = ws + 19228800;            // M_TAB*H
    float* rtab = ws + 20457600;            // M_TAB*64 = 131,072
    float* de   = ws + 20588672;            // E
    float* ce   = ws + 20652672;            // E
    float* sums = ws + 20716672;            // B*H = 76,800
    float* cnt  = ws + 20793472;            // B
    // total ~20.79M floats = 83.2 MB

    const int* src = eidx;
    const int* dst = eidx + E_EDGES;

    const int QH = H_DIM / 4;
    const dim3 blk(256);
    const int NT = (H_DIM + BN - 1) / BN;        // 10 col tiles
    const int MT_N   = (N_ATOMS + BM - 1) / BM;  // 157
    const int MT_TAB = M_TAB / BM;               // 32
    const int MT_B   = (B_MOLS + BM - 1) / BM;   // 2

    init_h_k   <<<(N_ATOMS * QH + 255) / 256, blk, 0, stream>>>(z, emb, h);
    edge_geom_k<<<(E_EDGES + 255) / 256,      blk, 0, stream>>>(pos, src, dst, de, ce);
    rbf_tab_k  <<<(M_TAB * 64 + 255) / 256,   blk, 0, stream>>>(rtab);

    for (int k = 0; k < L_LAYERS; ++k) {
        const float* w1 = mlp_w1 + (size_t)k * G_DIM * H_DIM;
        const float* b1 = mlp_b1 + (size_t)k * H_DIM;
        const float* w2 = mlp_w2 + (size_t)k * H_DIM * H_DIM;
        const float* b2 = mlp_b2 + (size_t)k * H_DIM;
        const float* l1 = lin1_w + (size_t)k * H_DIM * H_DIM;
        const float* l2 = lin2_w + (size_t)k * H_DIM * H_DIM;
        const float* l2b= lin2_b + (size_t)k * H_DIM;
        const float* iw = intw   + (size_t)k * H_DIM * H_DIM;
        const float* ib = intb   + (size_t)k * H_DIM;

        // filter table: ttab = ssp(rtab @ w1 + b1); wtab = ttab @ w2 + b2
        gemm_k<true, true, false><<<dim3(NT, MT_TAB), blk, 0, stream>>>(
            rtab, 64, w1, b1, ttab, M_TAB, G_DIM, H_DIM);
        gemm_k<true, false, false><<<dim3(NT, MT_TAB), blk, 0, stream>>>(
            ttab, H_DIM, w2, b2, wtab, M_TAB, H_DIM, H_DIM);

        // y = h @ lin1
        gemm_k<false, false, false><<<dim3(NT, MT_N), blk, 0, stream>>>(
            h, H_DIM, l1, nullptr, y, N_ATOMS, H_DIM, H_DIM);

        // agg = scatter_add(y[src] * W(d) * C)
        hipMemsetAsync(agg, 0, (size_t)N_ATOMS * H_DIM * sizeof(float), stream);
        scatter_k<<<(E_EDGES * QH + 255) / 256, blk, 0, stream>>>(
            y, wtab, de, ce, src, dst, agg);

        // y = ssp(agg @ lin2 + b);  h += y @ int_lin + b
        gemm_k<true, true, false><<<dim3(NT, MT_N), blk, 0, stream>>>(
            agg, H_DIM, l2, l2b, y, N_ATOMS, H_DIM, H_DIM);
        gemm_k<true, false, true><<<dim3(NT, MT_N), blk, 0, stream>>>(
            y, H_DIM, iw, ib, h, N_ATOMS, H_DIM, H_DIM);
    }

    // mean pool per molecule, then out = pooled @ pool_w + pool_b
    hipMemsetAsync(sums, 0, (size_t)(B_MOLS * H_DIM + B_MOLS) * sizeof(float), stream);
    pool_sum_k<<<(N_ATOMS * QH + 255) / 256, blk, 0, stream>>>(h, batch, sums);
    cnt_k     <<<(N_ATOMS + 255) / 256,      blk, 0, stream>>>(batch, cnt);
    pool_div_k<<<(B_MOLS * H_DIM + 255) / 256, blk, 0, stream>>>(sums, cnt);
    gemm_k<true, false, false><<<dim3(NT, MT_B), blk, 0, stream>>>(
        sums, H_DIM, poolw, poolb, (float*)d_out, B_MOLS, H_DIM, H_DIM);
}

// Round 2
// 3361.301 us; speedup vs baseline: 1.8717x; 1.8717x over previous
//
#include <hip/hip_runtime.h>
#include <math.h>

// SchNet forward, MI355X fp32. Round 2: scatter-add (atomic-bound, 537us/layer)
// replaced by CSR gather (build CSR by dst once per call; edges identical
// across layers). Filter W(d) tabulated at 2048 pts + lerp (round 1, verified
// absmax 2.4e-4 vs 1.44e-3 budget).

#define N_ATOMS 10000
#define E_EDGES 64000
#define B_MOLS  128
#define H_DIM   600
#define G_DIM   50
#define L_LAYERS 6
#define M_TAB   2048
#define DMAX    8.67f          // max possible d = sqrt(75) = 8.66025
#define LOG2C   0.69314718056f

#define BM 64
#define BN 64
#define BK 16

__device__ __forceinline__ float sspf(float x) {
    return fmaxf(x, 0.0f) + log1pf(expf(-fabsf(x))) - LOG2C;
}

// ---------------------------------------------------------------- GEMM
// out[Ma,Nc] = op(A[Ma,K](lda) @ W[K,Nc] + bias), op in {id, ssp}, optional +=
template<bool BIAS, bool ACT, bool ACCUM>
__global__ __launch_bounds__(256)
void gemm_k(const float* __restrict__ A, int lda,
            const float* __restrict__ W,
            const float* __restrict__ bias,
            float* __restrict__ out,
            int Ma, int K, int Nc)
{
    __shared__ __align__(16) float As[BK][BM];   // transposed: As[k][m]
    __shared__ __align__(16) float Bs[BK][BN];   // Bs[k][n]

    const int tid = threadIdx.x;
    const int tx = tid & 15, ty = tid >> 4;
    const int m0 = blockIdx.y * BM, n0 = blockIdx.x * BN;

    const int ar = tid >> 2;          // 0..63
    const int ac = (tid & 3) << 2;    // 0,4,8,12
    const int br = tid >> 4;          // 0..15
    const int bc = (tid & 15) << 2;   // 0..60

    float acc[4][4] = {};

    for (int k0 = 0; k0 < K; k0 += BK) {
        {
            int row = m0 + ar;
            int col = k0 + ac;
            float4 v = make_float4(0.f, 0.f, 0.f, 0.f);
            if (row < Ma) {
                const float* ap = A + (size_t)row * lda + col;
                if (col + 3 < K) {
                    v = *(const float4*)ap;
                } else {
                    if (col + 0 < K) v.x = ap[0];
                    if (col + 1 < K) v.y = ap[1];
                    if (col + 2 < K) v.z = ap[2];
                    if (col + 3 < K) v.w = ap[3];
                }
            }
            As[ac + 0][ar] = v.x;
            As[ac + 1][ar] = v.y;
            As[ac + 2][ar] = v.z;
            As[ac + 3][ar] = v.w;
        }
        {
            int row = k0 + br;
            int col = n0 + bc;
            float4 v = make_float4(0.f, 0.f, 0.f, 0.f);
            if (row < K) {
                const float* wp = W + (size_t)row * Nc + col;
                if (col + 3 < Nc) {
                    v = *(const float4*)wp;
                } else {
                    if (col + 0 < Nc) v.x = wp[0];
                    if (col + 1 < Nc) v.y = wp[1];
                    if (col + 2 < Nc) v.z = wp[2];
                    if (col + 3 < Nc) v.w = wp[3];
                }
            }
            *(float4*)&Bs[br][bc] = v;
        }
        __syncthreads();

        #pragma unroll
        for (int kk = 0; kk < BK; ++kk) {
            float4 a4 = *(const float4*)&As[kk][ty << 2];
            float4 b4 = *(const float4*)&Bs[kk][tx << 2];
            float av[4] = {a4.x, a4.y, a4.z, a4.w};
            float bv[4] = {b4.x, b4.y, b4.z, b4.w};
            #pragma unroll
            for (int i = 0; i < 4; ++i)
                #pragma unroll
                for (int j = 0; j < 4; ++j)
                    acc[i][j] = fmaf(av[i], bv[j], acc[i][j]);
        }
        __syncthreads();
    }

    #pragma unroll
    for (int i = 0; i < 4; ++i) {
        int row = m0 + (ty << 2) + i;
        if (row >= Ma) continue;
        int col = n0 + (tx << 2);
        float* op = out + (size_t)row * Nc + col;
        if (col + 3 < Nc) {
            float vals[4];
            #pragma unroll
            for (int j = 0; j < 4; ++j) {
                float v = acc[i][j];
                if constexpr (BIAS) v += bias[col + j];
                if constexpr (ACT)  v = sspf(v);
                vals[j] = v;
            }
            float4 o;
            if constexpr (ACCUM) {
                float4 prev = *(const float4*)op;
                o = make_float4(vals[0] + prev.x, vals[1] + prev.y,
                                vals[2] + prev.z, vals[3] + prev.w);
            } else {
                o = make_float4(vals[0], vals[1], vals[2], vals[3]);
            }
            *(float4*)op = o;
        } else {
            #pragma unroll
            for (int j = 0; j < 4; ++j) {
                int cj = col + j;
                if (cj < Nc) {
                    float v = acc[i][j];
                    if constexpr (BIAS) v += bias[cj];
                    if constexpr (ACT)  v = sspf(v);
                    if constexpr (ACCUM) v += op[j];
                    op[j] = v;
                }
            }
        }
    }
}

// ---------------------------------------------------------------- helpers
__global__ __launch_bounds__(256)
void init_h_k(const int* __restrict__ z, const float* __restrict__ emb,
              float* __restrict__ h)
{
    int t = blockIdx.x * 256 + threadIdx.x;
    const int QH = H_DIM / 4;
    if (t >= N_ATOMS * QH) return;
    int i = t / QH;
    int q = (t - i * QH) << 2;
    *(float4*)(h + (size_t)i * H_DIM + q) =
        *(const float4*)(emb + (size_t)z[i] * H_DIM + q);
}

// per-edge packed record: {src*H as int, i0*H as int, f*C, C}
__global__ __launch_bounds__(256)
void edge_geom_k(const float* __restrict__ pos, const int* __restrict__ src,
                 const int* __restrict__ dst, float4* __restrict__ einfo)
{
    int e = blockIdx.x * 256 + threadIdx.x;
    if (e >= E_EDGES) return;
    int s = src[e], d0 = dst[e];
    float dx = pos[s * 3 + 0] - pos[d0 * 3 + 0];
    float dy = pos[s * 3 + 1] - pos[d0 * 3 + 1];
    float dz = pos[s * 3 + 2] - pos[d0 * 3 + 2];
    float dist = sqrtf(dx * dx + dy * dy + dz * dz + 1e-12f);
    float cc = 0.5f * (cosf(dist * 0.31415926535f) + 1.0f);   // pi/CUTOFF
    float u = dist * ((float)(M_TAB - 1) / DMAX);
    u = fminf(fmaxf(u, 0.0f), (float)(M_TAB - 1) - 0.001f);
    int i0 = (int)u;
    float f = u - (float)i0;
    einfo[e] = make_float4(__int_as_float(s * H_DIM),
                           __int_as_float(i0 * H_DIM),
                           f * cc, cc);
}

__global__ __launch_bounds__(256)
void rbf_tab_k(float* __restrict__ rtab)
{
    int t = blockIdx.x * 256 + threadIdx.x;
    if (t >= M_TAB * 64) return;
    int i = t >> 6, g = t & 63;
    float v = 0.0f;
    if (g < G_DIM) {
        float dg  = (float)i * (DMAX / (float)(M_TAB - 1));
        float off = (float)g * (10.0f / 49.0f);
        float x = dg - off;
        const float coeff = -0.5f * (49.0f / 10.0f) * (49.0f / 10.0f);
        v = expf(coeff * x * x);
    }
    rtab[t] = v;
}

// ---------------------------------------------------------------- CSR build
__global__ __launch_bounds__(256)
void hist_k(const int* __restrict__ dst, int* __restrict__ deg)
{
    int e = blockIdx.x * 256 + threadIdx.x;
    if (e >= E_EDGES) return;
    atomicAdd(&deg[dst[e]], 1);
}

// one block of 1024 threads: exclusive scan of deg[0..N) -> rowptr[0..N]
__global__ __launch_bounds__(1024)
void scan_k(const int* __restrict__ deg, int* __restrict__ rowptr)
{
    __shared__ int sums[1024];
    const int CH = (N_ATOMS + 1023) / 1024 + 1;   // 10+1 slack to cover idx==N
    int tid = threadIdx.x;
    int base = tid * ((N_ATOMS + 1023) / 1024);   // chunk of 10
    const int CHUNK = (N_ATOMS + 1023) / 1024;    // 10
    int local[16];
    int s = 0;
    #pragma unroll
    for (int c = 0; c < 16; ++c) {
        if (c >= CHUNK) break;
        int idx = base + c;
        local[c] = s;
        s += (idx < N_ATOMS) ? deg[idx] : 0;
    }
    sums[tid] = s;
    __syncthreads();
    for (int off = 1; off < 1024; off <<= 1) {
        int v = (tid >= off) ? sums[tid - off] : 0;
        __syncthreads();
        sums[tid] += v;
        __syncthreads();
    }
    int prefix = (tid > 0) ? sums[tid - 1] : 0;
    #pragma unroll
    for (int c = 0; c < 16; ++c) {
        if (c >= CHUNK) break;
        int idx = base + c;
        if (idx <= N_ATOMS) rowptr[idx] = prefix + local[c];
    }
    if (tid == 1023) rowptr[N_ATOMS] = sums[1023];
    (void)CH;
}

// scatter each edge's record into its CSR slot
__global__ __launch_bounds__(256)
void fill_k(const int* __restrict__ dst, const float4* __restrict__ einfo,
            const int* __restrict__ rowptr, int* __restrict__ cursor,
            float4* __restrict__ esorted)
{
    int e = blockIdx.x * 256 + threadIdx.x;
    if (e >= E_EDGES) return;
    int d0 = dst[e];
    int pos = rowptr[d0] + atomicAdd(&cursor[d0], 1);
    esorted[pos] = einfo[e];
}

// ---------------------------------------------------------------- gather
// agg[i][q..q+3] = sum over in-edges e of y[src][q..] * (w0*C + fC*(w1-w0))
__global__ __launch_bounds__(256)
void gather_k(const float* __restrict__ y, const float* __restrict__ wt,
              const int* __restrict__ rowptr, const float4* __restrict__ esorted,
              float* __restrict__ agg)
{
    int t = blockIdx.x * 256 + threadIdx.x;
    const int QH = H_DIM / 4;
    if (t >= N_ATOMS * QH) return;
    int i = t / QH;
    int q = (t - i * QH) << 2;
    int j0 = rowptr[i], j1 = rowptr[i + 1];
    float4 acc = make_float4(0.f, 0.f, 0.f, 0.f);
    for (int j = j0; j < j1; ++j) {
        float4 ei = esorted[j];
        int srow = __float_as_int(ei.x);
        int wrow = __float_as_int(ei.y);
        float fc = ei.z, cc = ei.w;
        const float4 yv = *(const float4*)(y + srow + q);
        const float4 w0 = *(const float4*)(wt + wrow + q);
        const float4 w1 = *(const float4*)(wt + wrow + H_DIM + q);
        acc.x += yv.x * (w0.x * cc + fc * (w1.x - w0.x));
        acc.y += yv.y * (w0.y * cc + fc * (w1.y - w0.y));
        acc.z += yv.z * (w0.z * cc + fc * (w1.z - w0.z));
        acc.w += yv.w * (w0.w * cc + fc * (w1.w - w0.w));
    }
    *(float4*)(agg + (size_t)i * H_DIM + q) = acc;
}

// ---------------------------------------------------------------- pool
__global__ __launch_bounds__(256)
void pool_sum_k(const float* __restrict__ h, const int* __restrict__ batch,
                float* __restrict__ sums)
{
    int t = blockIdx.x * 256 + threadIdx.x;
    const int QH = H_DIM / 4;
    if (t >= N_ATOMS * QH) return;
    int i = t / QH;
    int q = (t - i * QH) << 2;
    int b = batch[i];
    const float4 hv = *(const float4*)(h + (size_t)i * H_DIM + q);
    float* sp = sums + (size_t)b * H_DIM + q;
    atomicAdd(sp + 0, hv.x);
    atomicAdd(sp + 1, hv.y);
    atomicAdd(sp + 2, hv.z);
    atomicAdd(sp + 3, hv.w);
}

__global__ __launch_bounds__(256)
void cnt_k(const int* __restrict__ batch, float* __restrict__ cnt)
{
    int i = blockIdx.x * 256 + threadIdx.x;
    if (i >= N_ATOMS) return;
    atomicAdd(&cnt[batch[i]], 1.0f);
}

__global__ __launch_bounds__(256)
void pool_div_k(float* __restrict__ sums, const float* __restrict__ cnt)
{
    int t = blockIdx.x * 256 + threadIdx.x;
    if (t >= B_MOLS * H_DIM) return;
    sums[t] /= fmaxf(cnt[t / H_DIM], 1.0f);
}

// ---------------------------------------------------------------- launch
extern "C" void kernel_launch(void* const* d_in, const int* in_sizes, int n_in,
                              void* d_out, int out_size, void* d_ws, size_t ws_size,
                              hipStream_t stream)
{
    const int*   z      = (const int*)  d_in[0];
    const float* pos    = (const float*)d_in[1];
    const int*   batch  = (const int*)  d_in[2];
    const int*   eidx   = (const int*)  d_in[3];
    const float* emb    = (const float*)d_in[4];
    const float* mlp_w1 = (const float*)d_in[5];
    const float* mlp_b1 = (const float*)d_in[6];
    const float* mlp_w2 = (const float*)d_in[7];
    const float* mlp_b2 = (const float*)d_in[8];
    const float* lin1_w = (const float*)d_in[9];
    const float* lin2_w = (const float*)d_in[10];
    const float* lin2_b = (const float*)d_in[11];
    const float* intw   = (const float*)d_in[12];
    const float* intb   = (const float*)d_in[13];
    const float* poolw  = (const float*)d_in[14];
    const float* poolb  = (const float*)d_in[15];

    float* ws     = (float*)d_ws;
    float* h      = ws;                      // 6,000,000
    float* y      = ws + 6000000;            // 6,000,000
    float* agg    = ws + 12000000;           // 6,000,000
    float* ttab   = ws + 18000000;           // 1,228,800
    float* wtab   = ws + 19228800;           // 1,228,800
    float* rtab   = ws + 20457600;           // 131,072
    float4* einfo   = (float4*)(ws + 20588672);  // E*4 = 256,000 floats
    float4* esorted = (float4*)(ws + 20844672);  // 256,000 floats
    float* sums   = ws + 21100672;           // 76,800
    float* cnt    = ws + 21177472;           // 128
    int*   deg    = (int*)(ws + 21177600);   // 10,000
    int*   cursor = (int*)(ws + 21187600);   // 10,000
    int*   rowptr = (int*)(ws + 21197600);   // 10,001
    // total ~21.21M floats = 84.8 MB

    const int* src = eidx;
    const int* dst = eidx + E_EDGES;

    const int QH = H_DIM / 4;
    const dim3 blk(256);
    const int NT = (H_DIM + BN - 1) / BN;        // 10
    const int MT_N   = (N_ATOMS + BM - 1) / BM;  // 157
    const int MT_TAB = M_TAB / BM;               // 32
    const int MT_B   = (B_MOLS + BM - 1) / BM;   // 2

    // ---- one-time prep (per call)
    init_h_k   <<<(N_ATOMS * QH + 255) / 256, blk, 0, stream>>>(z, emb, h);
    edge_geom_k<<<(E_EDGES + 255) / 256,      blk, 0, stream>>>(pos, src, dst, einfo);
    rbf_tab_k  <<<(M_TAB * 64 + 255) / 256,   blk, 0, stream>>>(rtab);
    hipMemsetAsync(deg, 0, 2 * N_ATOMS * sizeof(int), stream);   // deg + cursor
    hist_k <<<(E_EDGES + 255) / 256, blk, 0, stream>>>(dst, deg);
    scan_k <<<1, 1024, 0, stream>>>(deg, rowptr);
    fill_k <<<(E_EDGES + 255) / 256, blk, 0, stream>>>(dst, einfo, rowptr, cursor, esorted);

    for (int k = 0; k < L_LAYERS; ++k) {
        const float* w1 = mlp_w1 + (size_t)k * G_DIM * H_DIM;
        const float* b1 = mlp_b1 + (size_t)k * H_DIM;
        const float* w2 = mlp_w2 + (size_t)k * H_DIM * H_DIM;
        const float* b2 = mlp_b2 + (size_t)k * H_DIM;
        const float* l1 = lin1_w + (size_t)k * H_DIM * H_DIM;
        const float* l2 = lin2_w + (size_t)k * H_DIM * H_DIM;
        const float* l2b= lin2_b + (size_t)k * H_DIM;
        const float* iw = intw   + (size_t)k * H_DIM * H_DIM;
        const float* ib = intb   + (size_t)k * H_DIM;

        // filter table: ttab = ssp(rtab @ w1 + b1); wtab = ttab @ w2 + b2
        gemm_k<true, true, false><<<dim3(NT, MT_TAB), blk, 0, stream>>>(
            rtab, 64, w1, b1, ttab, M_TAB, G_DIM, H_DIM);
        gemm_k<true, false, false><<<dim3(NT, MT_TAB), blk, 0, stream>>>(
            ttab, H_DIM, w2, b2, wtab, M_TAB, H_DIM, H_DIM);

        // y = h @ lin1
        gemm_k<false, false, false><<<dim3(NT, MT_N), blk, 0, stream>>>(
            h, H_DIM, l1, nullptr, y, N_ATOMS, H_DIM, H_DIM);

        // agg[i] = sum_{e: dst=i} y[src_e] * W(d_e) * C_e   (CSR gather, no atomics)
        gather_k<<<(N_ATOMS * QH + 255) / 256, blk, 0, stream>>>(
            y, wtab, rowptr, esorted, agg);

        // y = ssp(agg @ lin2 + b);  h += y @ int_lin + b
        gemm_k<true, true, false><<<dim3(NT, MT_N), blk, 0, stream>>>(
            agg, H_DIM, l2, l2b, y, N_ATOMS, H_DIM, H_DIM);
        gemm_k<true, false, true><<<dim3(NT, MT_N), blk, 0, stream>>>(
            y, H_DIM, iw, ib, h, N_ATOMS, H_DIM, H_DIM);
    }

    // mean pool per molecule, then out = pooled @ pool_w + pool_b
    hipMemsetAsync(sums, 0, (size_t)(B_MOLS * H_DIM + B_MOLS) * sizeof(float), stream);
    pool_sum_k<<<(N_ATOMS * QH + 255) / 256, blk, 0, stream>>>(h, batch, sums);
    cnt_k     <<<(N_ATOMS + 255) / 256,      blk, 0, stream>>>(batch, cnt);
    pool_div_k<<<(B_MOLS * H_DIM + 255) / 256, blk, 0, stream>>>(sums, cnt);
    gemm_k<true, false, false><<<dim3(NT, MT_B), blk, 0, stream>>>(
        sums, H_DIM, poolw, poolb, (float*)d_out, B_MOLS, H_DIM, H_DIM);
}

// Round 3
// 2881.889 us; speedup vs baseline: 2.1831x; 1.1664x over previous
//
#include <hip/hip_runtime.h>
#include <math.h>

// SchNet forward, MI355X. Round 3: node/table GEMMs moved to split-bf16 MFMA
// (A*B ~ Ah*Bh + Ah*Bl + Al*Bh, rel err ~2^-15). Weights pre-split+transposed
// to [N][K] bf16 hi/lo once per call; producers (init_h, gather, epilogues)
// emit split operands so the GEMM K-loop is pure load/ds_read_b128/MFMA.
// CSR gather (round 2) and filter table + lerp (round 1) retained.

#define N_ATOMS 10000
#define E_EDGES 64000
#define B_MOLS  128
#define H_DIM   600
#define G_DIM   50
#define L_LAYERS 6
#define M_TAB   2048
#define DMAX    8.67f
#define LOG2C   0.69314718056f

// MFMA GEMM tiling
#define TM 128
#define TN 128
#define TK 32
#define SA 40          // LDS row stride in shorts (32 + 8 pad; 80B = 16B-aligned rows)

typedef __attribute__((ext_vector_type(8))) short bf16x8;
typedef __attribute__((ext_vector_type(4))) float f32x4;

__device__ __forceinline__ float sspf(float x) {
    return fmaxf(x, 0.0f) + log1pf(expf(-fabsf(x))) - LOG2C;
}

__device__ __forceinline__ short f2bf(float x) {
    unsigned u = __float_as_uint(x);
    unsigned r = (u + 0x7FFF + ((u >> 16) & 1)) >> 16;   // RNE
    return (short)r;
}
__device__ __forceinline__ float bf2f(short h) {
    return __uint_as_float(((unsigned)(unsigned short)h) << 16);
}
__device__ __forceinline__ void split2(float x, short& hi, short& lo) {
    hi = f2bf(x);
    lo = f2bf(x - bf2f(hi));
}

// ---------------------------------------------------------------- MFMA GEMM
// out[Ma,Nc] = op(A[Ma,K] @ B[K,Nc] + bias); A given as bf16 hi/lo [Ma][lda],
// B given TRANSPOSED as bf16 hi/lo [Nc][ldb] (row n holds K k-contiguous).
template<bool BIAS, bool ACT, bool ACCUM, bool WF32, bool WSPLIT>
__global__ __launch_bounds__(256, 2)
void gemm_mfma(const short* __restrict__ Ah, const short* __restrict__ Al, int lda,
               const short* __restrict__ Bh, const short* __restrict__ Bl, int ldb,
               const float* __restrict__ bias,
               float* __restrict__ outF, short* __restrict__ outH,
               short* __restrict__ outL,
               int Ma, int K, int Nc)
{
    __shared__ __align__(16) short As[2][TM * SA];   // [hi/lo][m][k]
    __shared__ __align__(16) short Bs[2][TN * SA];   // [hi/lo][n][k]

    const int tid = threadIdx.x;
    const int m0 = blockIdx.y * TM, n0 = blockIdx.x * TN;
    const int wid = tid >> 6, lane = tid & 63;
    const int wm = (wid >> 1) * 64, wn = (wid & 1) * 64;
    const int l15 = lane & 15, quad = lane >> 4;

    f32x4 acc[4][4];
    #pragma unroll
    for (int i = 0; i < 4; ++i)
        #pragma unroll
        for (int j = 0; j < 4; ++j)
            acc[i][j] = (f32x4){0.f, 0.f, 0.f, 0.f};

    // staging map (A and B identical geometry: 128 rows x 32 k)
    const int srow = tid >> 3;          // 0..31 (+32*pass)
    const int skk  = (tid & 7) << 2;    // 0,4,..,28

    for (int k0 = 0; k0 < K; k0 += TK) {
        #pragma unroll
        for (int p = 0; p < 4; ++p) {
            int m = p * 32 + srow;
            int gm = m0 + m, gk = k0 + skk;
            short4 vh = {0, 0, 0, 0}, vl = {0, 0, 0, 0};
            if (gm < Ma) {
                const short* ph = Ah + (size_t)gm * lda + gk;
                const short* pl = Al + (size_t)gm * lda + gk;
                if (gk + 3 < K) {
                    vh = *(const short4*)ph; vl = *(const short4*)pl;
                } else {
                    if (gk + 0 < K) { vh.x = ph[0]; vl.x = pl[0]; }
                    if (gk + 1 < K) { vh.y = ph[1]; vl.y = pl[1]; }
                    if (gk + 2 < K) { vh.z = ph[2]; vl.z = pl[2]; }
                }
            }
            *(short4*)&As[0][m * SA + skk] = vh;
            *(short4*)&As[1][m * SA + skk] = vl;
        }
        #pragma unroll
        for (int p = 0; p < 4; ++p) {
            int n = p * 32 + srow;
            int gn = n0 + n, gk = k0 + skk;
            short4 vh = {0, 0, 0, 0}, vl = {0, 0, 0, 0};
            if (gn < Nc) {
                const short* ph = Bh + (size_t)gn * ldb + gk;
                const short* pl = Bl + (size_t)gn * ldb + gk;
                if (gk + 3 < K) {
                    vh = *(const short4*)ph; vl = *(const short4*)pl;
                } else {
                    if (gk + 0 < K) { vh.x = ph[0]; vl.x = pl[0]; }
                    if (gk + 1 < K) { vh.y = ph[1]; vl.y = pl[1]; }
                    if (gk + 2 < K) { vh.z = ph[2]; vl.z = pl[2]; }
                }
            }
            *(short4*)&Bs[0][n * SA + skk] = vh;
            *(short4*)&Bs[1][n * SA + skk] = vl;
        }
        __syncthreads();

        bf16x8 a_h[4], a_l[4], b_h[4], b_l[4];
        #pragma unroll
        for (int mi = 0; mi < 4; ++mi) {
            int row = wm + mi * 16 + l15;
            a_h[mi] = *(const bf16x8*)&As[0][row * SA + quad * 8];
            a_l[mi] = *(const bf16x8*)&As[1][row * SA + quad * 8];
        }
        #pragma unroll
        for (int ni = 0; ni < 4; ++ni) {
            int col = wn + ni * 16 + l15;
            b_h[ni] = *(const bf16x8*)&Bs[0][col * SA + quad * 8];
            b_l[ni] = *(const bf16x8*)&Bs[1][col * SA + quad * 8];
        }
        #pragma unroll
        for (int mi = 0; mi < 4; ++mi)
            #pragma unroll
            for (int ni = 0; ni < 4; ++ni) {
                acc[mi][ni] = __builtin_amdgcn_mfma_f32_16x16x32_bf16(
                    a_h[mi], b_h[ni], acc[mi][ni], 0, 0, 0);
                acc[mi][ni] = __builtin_amdgcn_mfma_f32_16x16x32_bf16(
                    a_h[mi], b_l[ni], acc[mi][ni], 0, 0, 0);
                acc[mi][ni] = __builtin_amdgcn_mfma_f32_16x16x32_bf16(
                    a_l[mi], b_h[ni], acc[mi][ni], 0, 0, 0);
            }
        __syncthreads();
    }

    // epilogue: C/D layout col = lane&15, row = quad*4 + r
    #pragma unroll
    for (int mi = 0; mi < 4; ++mi) {
        #pragma unroll
        for (int r = 0; r < 4; ++r) {
            int row = m0 + wm + mi * 16 + quad * 4 + r;
            if (row >= Ma) continue;
            #pragma unroll
            for (int ni = 0; ni < 4; ++ni) {
                int col = n0 + wn + ni * 16 + l15;
                if (col >= Nc) continue;
                float v = acc[mi][ni][r];
                if constexpr (BIAS) v += bias[col];
                if constexpr (ACT)  v = sspf(v);
                size_t idx = (size_t)row * Nc + col;
                if constexpr (ACCUM) v += outF[idx];
                if constexpr (WF32)  outF[idx] = v;
                if constexpr (WSPLIT) {
                    short hh, ll; split2(v, hh, ll);
                    outH[idx] = hh; outL[idx] = ll;
                }
            }
        }
    }
}

// ---------------------------------------------------------------- fp32 GEMM (pool only)
#define BM 64
#define BN 64
#define BK 16
template<bool BIAS>
__global__ __launch_bounds__(256)
void gemm_k(const float* __restrict__ A, int lda,
            const float* __restrict__ W,
            const float* __restrict__ bias,
            float* __restrict__ out,
            int Ma, int K, int Nc)
{
    __shared__ __align__(16) float Asd[BK][BM];
    __shared__ __align__(16) float Bsd[BK][BN];
    const int tid = threadIdx.x;
    const int tx = tid & 15, ty = tid >> 4;
    const int m0 = blockIdx.y * BM, n0 = blockIdx.x * BN;
    const int ar = tid >> 2, ac = (tid & 3) << 2;
    const int br = tid >> 4, bc = (tid & 15) << 2;
    float acc[4][4] = {};
    for (int k0 = 0; k0 < K; k0 += BK) {
        {
            int row = m0 + ar, col = k0 + ac;
            float4 v = make_float4(0.f, 0.f, 0.f, 0.f);
            if (row < Ma) {
                const float* ap = A + (size_t)row * lda + col;
                if (col + 3 < K) v = *(const float4*)ap;
                else {
                    if (col + 0 < K) v.x = ap[0];
                    if (col + 1 < K) v.y = ap[1];
                    if (col + 2 < K) v.z = ap[2];
                }
            }
            Asd[ac + 0][ar] = v.x; Asd[ac + 1][ar] = v.y;
            Asd[ac + 2][ar] = v.z; Asd[ac + 3][ar] = v.w;
        }
        {
            int row = k0 + br, col = n0 + bc;
            float4 v = make_float4(0.f, 0.f, 0.f, 0.f);
            if (row < K && col + 3 < Nc)
                v = *(const float4*)(W + (size_t)row * Nc + col);
            *(float4*)&Bsd[br][bc] = v;
        }
        __syncthreads();
        #pragma unroll
        for (int kk = 0; kk < BK; ++kk) {
            float4 a4 = *(const float4*)&Asd[kk][ty << 2];
            float4 b4 = *(const float4*)&Bsd[kk][tx << 2];
            float av[4] = {a4.x, a4.y, a4.z, a4.w};
            float bv[4] = {b4.x, b4.y, b4.z, b4.w};
            #pragma unroll
            for (int i = 0; i < 4; ++i)
                #pragma unroll
                for (int j = 0; j < 4; ++j)
                    acc[i][j] = fmaf(av[i], bv[j], acc[i][j]);
        }
        __syncthreads();
    }
    #pragma unroll
    for (int i = 0; i < 4; ++i) {
        int row = m0 + (ty << 2) + i;
        if (row >= Ma) continue;
        #pragma unroll
        for (int j = 0; j < 4; ++j) {
            int col = n0 + (tx << 2) + j;
            if (col >= Nc) continue;
            float v = acc[i][j];
            if constexpr (BIAS) v += bias[col];
            out[(size_t)row * Nc + col] = v;
        }
    }
}

// ---------------------------------------------------------------- weight prep
// transpose+split W[K][N] (fp32) -> out hi/lo [N][Kpad] bf16 (zero-padded k>=K)
__global__ __launch_bounds__(256)
void wts_w1_k(const float* __restrict__ w_all, short* __restrict__ oh,
              short* __restrict__ ol)
{
    // W = mlp_w1[layer]: [50][600] -> [600][64]
    __shared__ short th[64][65], tl[64][65];
    const int layer = blockIdx.z;
    const float* w = w_all + (size_t)layer * G_DIM * H_DIM;
    short* ohz = oh + (size_t)layer * H_DIM * 64;
    short* olz = ol + (size_t)layer * H_DIM * 64;
    const int n0 = blockIdx.y * 64;
    const int tid = threadIdx.x;
    #pragma unroll
    for (int p = 0; p < 4; ++p) {
        int k = p * 16 + (tid >> 4);
        int n4 = (tid & 15) << 2;
        float4 v = make_float4(0.f, 0.f, 0.f, 0.f);
        if (k < G_DIM && n0 + n4 + 3 < H_DIM)
            v = *(const float4*)(w + (size_t)k * H_DIM + n0 + n4);
        short hh, ll;
        split2(v.x, hh, ll); th[n4 + 0][k] = hh; tl[n4 + 0][k] = ll;
        split2(v.y, hh, ll); th[n4 + 1][k] = hh; tl[n4 + 1][k] = ll;
        split2(v.z, hh, ll); th[n4 + 2][k] = hh; tl[n4 + 2][k] = ll;
        split2(v.w, hh, ll); th[n4 + 3][k] = hh; tl[n4 + 3][k] = ll;
    }
    __syncthreads();
    #pragma unroll
    for (int p = 0; p < 4; ++p) {
        int n = p * 16 + (tid >> 4);
        int k4 = (tid & 15) << 2;
        if (n0 + n >= H_DIM) continue;
        short4 sh = { th[n][k4], th[n][k4 + 1], th[n][k4 + 2], th[n][k4 + 3] };
        short4 sl = { tl[n][k4], tl[n][k4 + 1], tl[n][k4 + 2], tl[n][k4 + 3] };
        *(short4*)(ohz + (size_t)(n0 + n) * 64 + k4) = sh;
        *(short4*)(olz + (size_t)(n0 + n) * 64 + k4) = sl;
    }
}

// big weights: z = type*6+layer; types: 0=mlp_w2 1=lin1 2=lin2 3=int; [600][600]
__global__ __launch_bounds__(256)
void wts_big_k(const float* __restrict__ w2, const float* __restrict__ l1,
               const float* __restrict__ l2, const float* __restrict__ iw,
               short* __restrict__ oh2, short* __restrict__ ol2,
               short* __restrict__ oh1, short* __restrict__ ol1,
               short* __restrict__ ohl2, short* __restrict__ oll2,
               short* __restrict__ ohi, short* __restrict__ oli)
{
    __shared__ short th[64][65], tl[64][65];
    const int z = blockIdx.z, type = z / L_LAYERS, layer = z % L_LAYERS;
    const float* w; short* oh; short* ol;
    if (type == 0)      { w = w2; oh = oh2; ol = ol2; }
    else if (type == 1) { w = l1; oh = oh1; ol = ol1; }
    else if (type == 2) { w = l2; oh = ohl2; ol = oll2; }
    else                { w = iw; oh = ohi; ol = oli; }
    w  += (size_t)layer * H_DIM * H_DIM;
    oh += (size_t)layer * H_DIM * H_DIM;
    ol += (size_t)layer * H_DIM * H_DIM;
    const int k0 = blockIdx.x * 64, n0 = blockIdx.y * 64;
    const int tid = threadIdx.x;
    #pragma unroll
    for (int p = 0; p < 4; ++p) {
        int k = p * 16 + (tid >> 4);
        int n4 = (tid & 15) << 2;
        float4 v = make_float4(0.f, 0.f, 0.f, 0.f);
        if (k0 + k < H_DIM && n0 + n4 + 3 < H_DIM)
            v = *(const float4*)(w + (size_t)(k0 + k) * H_DIM + n0 + n4);
        short hh, ll;
        split2(v.x, hh, ll); th[n4 + 0][k] = hh; tl[n4 + 0][k] = ll;
        split2(v.y, hh, ll); th[n4 + 1][k] = hh; tl[n4 + 1][k] = ll;
        split2(v.z, hh, ll); th[n4 + 2][k] = hh; tl[n4 + 2][k] = ll;
        split2(v.w, hh, ll); th[n4 + 3][k] = hh; tl[n4 + 3][k] = ll;
    }
    __syncthreads();
    #pragma unroll
    for (int p = 0; p < 4; ++p) {
        int n = p * 16 + (tid >> 4);
        int k4 = (tid & 15) << 2;
        if (n0 + n >= H_DIM || k0 + k4 >= H_DIM) continue;
        short4 sh = { th[n][k4], th[n][k4 + 1], th[n][k4 + 2], th[n][k4 + 3] };
        short4 sl = { tl[n][k4], tl[n][k4 + 1], tl[n][k4 + 2], tl[n][k4 + 3] };
        *(short4*)(oh + (size_t)(n0 + n) * H_DIM + k0 + k4) = sh;
        *(short4*)(ol + (size_t)(n0 + n) * H_DIM + k0 + k4) = sl;
    }
}

// ---------------------------------------------------------------- helpers
__global__ __launch_bounds__(256)
void init_h_k(const int* __restrict__ z, const float* __restrict__ emb,
              float* __restrict__ h, short* __restrict__ hh, short* __restrict__ hl)
{
    int t = blockIdx.x * 256 + threadIdx.x;
    const int QH = H_DIM / 4;
    if (t >= N_ATOMS * QH) return;
    int i = t / QH;
    int q = (t - i * QH) << 2;
    size_t idx = (size_t)i * H_DIM + q;
    float4 v = *(const float4*)(emb + (size_t)z[i] * H_DIM + q);
    *(float4*)(h + idx) = v;
    short4 sh, sl;
    split2(v.x, sh.x, sl.x); split2(v.y, sh.y, sl.y);
    split2(v.z, sh.z, sl.z); split2(v.w, sh.w, sl.w);
    *(short4*)(hh + idx) = sh;
    *(short4*)(hl + idx) = sl;
}

__global__ __launch_bounds__(256)
void edge_geom_k(const float* __restrict__ pos, const int* __restrict__ src,
                 const int* __restrict__ dst, float4* __restrict__ einfo)
{
    int e = blockIdx.x * 256 + threadIdx.x;
    if (e >= E_EDGES) return;
    int s = src[e], d0 = dst[e];
    float dx = pos[s * 3 + 0] - pos[d0 * 3 + 0];
    float dy = pos[s * 3 + 1] - pos[d0 * 3 + 1];
    float dz = pos[s * 3 + 2] - pos[d0 * 3 + 2];
    float dist = sqrtf(dx * dx + dy * dy + dz * dz + 1e-12f);
    float cc = 0.5f * (cosf(dist * 0.31415926535f) + 1.0f);
    float u = dist * ((float)(M_TAB - 1) / DMAX);
    u = fminf(fmaxf(u, 0.0f), (float)(M_TAB - 1) - 0.001f);
    int i0 = (int)u;
    float f = u - (float)i0;
    einfo[e] = make_float4(__int_as_float(s * H_DIM),
                           __int_as_float(i0 * H_DIM),
                           f * cc, cc);
}

// rbf table [M_TAB][64] bf16 hi/lo, zero for g >= 50
__global__ __launch_bounds__(256)
void rbf_tab_k(short* __restrict__ rh, short* __restrict__ rl)
{
    int t = blockIdx.x * 256 + threadIdx.x;
    if (t >= M_TAB * 64) return;
    int i = t >> 6, g = t & 63;
    float v = 0.0f;
    if (g < G_DIM) {
        float dg  = (float)i * (DMAX / (float)(M_TAB - 1));
        float off = (float)g * (10.0f / 49.0f);
        float x = dg - off;
        const float coeff = -0.5f * (49.0f / 10.0f) * (49.0f / 10.0f);
        v = expf(coeff * x * x);
    }
    short hh, ll; split2(v, hh, ll);
    rh[t] = hh; rl[t] = ll;
}

// ---------------------------------------------------------------- CSR build
__global__ __launch_bounds__(256)
void hist_k(const int* __restrict__ dst, int* __restrict__ deg)
{
    int e = blockIdx.x * 256 + threadIdx.x;
    if (e >= E_EDGES) return;
    atomicAdd(&deg[dst[e]], 1);
}

__global__ __launch_bounds__(1024)
void scan_k(const int* __restrict__ deg, int* __restrict__ rowptr)
{
    __shared__ int sums[1024];
    int tid = threadIdx.x;
    const int CHUNK = (N_ATOMS + 1023) / 1024;
    int base = tid * CHUNK;
    int local[16];
    int s = 0;
    #pragma unroll
    for (int c = 0; c < 16; ++c) {
        if (c >= CHUNK) break;
        int idx = base + c;
        local[c] = s;
        s += (idx < N_ATOMS) ? deg[idx] : 0;
    }
    sums[tid] = s;
    __syncthreads();
    for (int off = 1; off < 1024; off <<= 1) {
        int v = (tid >= off) ? sums[tid - off] : 0;
        __syncthreads();
        sums[tid] += v;
        __syncthreads();
    }
    int prefix = (tid > 0) ? sums[tid - 1] : 0;
    #pragma unroll
    for (int c = 0; c < 16; ++c) {
        if (c >= CHUNK) break;
        int idx = base + c;
        if (idx <= N_ATOMS) rowptr[idx] = prefix + local[c];
    }
    if (tid == 1023) rowptr[N_ATOMS] = sums[1023];
}

__global__ __launch_bounds__(256)
void fill_k(const int* __restrict__ dst, const float4* __restrict__ einfo,
            const int* __restrict__ rowptr, int* __restrict__ cursor,
            float4* __restrict__ esorted)
{
    int e = blockIdx.x * 256 + threadIdx.x;
    if (e >= E_EDGES) return;
    int d0 = dst[e];
    int pos = rowptr[d0] + atomicAdd(&cursor[d0], 1);
    esorted[pos] = einfo[e];
}

// ---------------------------------------------------------------- gather
__global__ __launch_bounds__(256)
void gather_k(const float* __restrict__ y, const float* __restrict__ wt,
              const int* __restrict__ rowptr, const float4* __restrict__ esorted,
              short* __restrict__ aggH, short* __restrict__ aggL)
{
    int t = blockIdx.x * 256 + threadIdx.x;
    const int QH = H_DIM / 4;
    if (t >= N_ATOMS * QH) return;
    int i = t / QH;
    int q = (t - i * QH) << 2;
    int j0 = rowptr[i], j1 = rowptr[i + 1];
    float4 acc = make_float4(0.f, 0.f, 0.f, 0.f);
    for (int j = j0; j < j1; ++j) {
        float4 ei = esorted[j];
        int srow = __float_as_int(ei.x);
        int wrow = __float_as_int(ei.y);
        float fc = ei.z, cc = ei.w;
        const float4 yv = *(const float4*)(y + srow + q);
        const float4 w0 = *(const float4*)(wt + wrow + q);
        const float4 w1 = *(const float4*)(wt + wrow + H_DIM + q);
        acc.x += yv.x * (w0.x * cc + fc * (w1.x - w0.x));
        acc.y += yv.y * (w0.y * cc + fc * (w1.y - w0.y));
        acc.z += yv.z * (w0.z * cc + fc * (w1.z - w0.z));
        acc.w += yv.w * (w0.w * cc + fc * (w1.w - w0.w));
    }
    short4 sh, sl;
    split2(acc.x, sh.x, sl.x); split2(acc.y, sh.y, sl.y);
    split2(acc.z, sh.z, sl.z); split2(acc.w, sh.w, sl.w);
    size_t idx = (size_t)i * H_DIM + q;
    *(short4*)(aggH + idx) = sh;
    *(short4*)(aggL + idx) = sl;
}

// ---------------------------------------------------------------- pool
__global__ __launch_bounds__(256)
void pool_sum_k(const float* __restrict__ h, const int* __restrict__ batch,
                float* __restrict__ sums)
{
    int t = blockIdx.x * 256 + threadIdx.x;
    const int QH = H_DIM / 4;
    if (t >= N_ATOMS * QH) return;
    int i = t / QH;
    int q = (t - i * QH) << 2;
    int b = batch[i];
    const float4 hv = *(const float4*)(h + (size_t)i * H_DIM + q);
    float* sp = sums + (size_t)b * H_DIM + q;
    atomicAdd(sp + 0, hv.x);
    atomicAdd(sp + 1, hv.y);
    atomicAdd(sp + 2, hv.z);
    atomicAdd(sp + 3, hv.w);
}

__global__ __launch_bounds__(256)
void cnt_k(const int* __restrict__ batch, float* __restrict__ cnt)
{
    int i = blockIdx.x * 256 + threadIdx.x;
    if (i >= N_ATOMS) return;
    atomicAdd(&cnt[batch[i]], 1.0f);
}

__global__ __launch_bounds__(256)
void pool_div_k(float* __restrict__ sums, const float* __restrict__ cnt)
{
    int t = blockIdx.x * 256 + threadIdx.x;
    if (t >= B_MOLS * H_DIM) return;
    sums[t] /= fmaxf(cnt[t / H_DIM], 1.0f);
}

// ---------------------------------------------------------------- launch
extern "C" void kernel_launch(void* const* d_in, const int* in_sizes, int n_in,
                              void* d_out, int out_size, void* d_ws, size_t ws_size,
                              hipStream_t stream)
{
    const int*   z      = (const int*)  d_in[0];
    const float* pos    = (const float*)d_in[1];
    const int*   batch  = (const int*)  d_in[2];
    const int*   eidx   = (const int*)  d_in[3];
    const float* emb    = (const float*)d_in[4];
    const float* mlp_w1 = (const float*)d_in[5];
    const float* mlp_b1 = (const float*)d_in[6];
    const float* mlp_w2 = (const float*)d_in[7];
    const float* mlp_b2 = (const float*)d_in[8];
    const float* lin1_w = (const float*)d_in[9];
    const float* lin2_w = (const float*)d_in[10];
    const float* lin2_b = (const float*)d_in[11];
    const float* intw   = (const float*)d_in[12];
    const float* intb   = (const float*)d_in[13];
    const float* poolw  = (const float*)d_in[14];
    const float* poolb  = (const float*)d_in[15];

    float* ws = (float*)d_ws;
    float*  h       = ws;                                   // 6,000,000 f
    float*  y1      = ws + 6000000;                         // 6,000,000 f
    short*  t_hi    = (short*)y1;                           // alias (post-gather)
    short*  t_lo    = t_hi + 6000000;
    short*  h_hi    = (short*)(ws + 12000000);              // 6M shorts
    short*  h_lo    = (short*)(ws + 15000000);
    short*  agg_hi  = (short*)(ws + 18000000);
    short*  agg_lo  = (short*)(ws + 21000000);
    short*  ttab_hi = (short*)(ws + 24000000);              // 1,228,800 shorts
    short*  ttab_lo = (short*)(ws + 24614400);
    float*  wtab    = ws + 25228800;                        // 1,228,800 f
    short*  rtab_hi = (short*)(ws + 26457600);              // 131,072 shorts
    short*  rtab_lo = (short*)(ws + 26523136);
    short*  wt_hi   = (short*)(ws + 26588672);              // 8,870,400 shorts
    short*  wt_lo   = (short*)(ws + 31023872);
    float4* einfo   = (float4*)(ws + 35459072);             // 256,000 f
    float4* esorted = (float4*)(ws + 35715072);             // 256,000 f
    float*  sums    = ws + 35971072;                        // 76,800 f
    float*  cnt     = ws + 36047872;                        // 128 f
    int*    deg     = (int*)(ws + 36048000);
    int*    cursor  = (int*)(ws + 36058000);
    int*    rowptr  = (int*)(ws + 36068000);
    // total ~36.08M floats = 144.3 MB

    // split-weight sub-offsets (shorts): [w1t | w2t | l1t | l2t | intt]
    short* w1t_h = wt_hi;                 short* w1t_l = wt_lo;                 // 6*600*64
    short* w2t_h = wt_hi + 230400;        short* w2t_l = wt_lo + 230400;        // 6*360000
    short* l1t_h = wt_hi + 2390400;       short* l1t_l = wt_lo + 2390400;
    short* l2t_h = wt_hi + 4550400;       short* l2t_l = wt_lo + 4550400;
    short* int_h = wt_hi + 6710400;       short* int_l = wt_lo + 6710400;

    const int* src = eidx;
    const int* dst = eidx + E_EDGES;

    const int QH = H_DIM / 4;
    const dim3 blk(256);
    const int GN  = (H_DIM + TN - 1) / TN;     // 5
    const int GMN = (N_ATOMS + TM - 1) / TM;   // 79
    const int GMT = M_TAB / TM;                // 16

    // ---- one-time prep (per call)
    init_h_k   <<<(N_ATOMS * QH + 255) / 256, blk, 0, stream>>>(z, emb, h, h_hi, h_lo);
    edge_geom_k<<<(E_EDGES + 255) / 256,      blk, 0, stream>>>(pos, src, dst, einfo);
    rbf_tab_k  <<<(M_TAB * 64 + 255) / 256,   blk, 0, stream>>>(rtab_hi, rtab_lo);
    hipMemsetAsync(deg, 0, 2 * N_ATOMS * sizeof(int), stream);
    hist_k <<<(E_EDGES + 255) / 256, blk, 0, stream>>>(dst, deg);
    scan_k <<<1, 1024, 0, stream>>>(deg, rowptr);
    fill_k <<<(E_EDGES + 255) / 256, blk, 0, stream>>>(dst, einfo, rowptr, cursor, esorted);
    wts_w1_k  <<<dim3(1, 10, 6),  blk, 0, stream>>>(mlp_w1, w1t_h, w1t_l);
    wts_big_k <<<dim3(10, 10, 24), blk, 0, stream>>>(
        mlp_w2, lin1_w, lin2_w, intw,
        w2t_h, w2t_l, l1t_h, l1t_l, l2t_h, l2t_l, int_h, int_l);

    for (int k = 0; k < L_LAYERS; ++k) {
        const float* b1  = mlp_b1 + (size_t)k * H_DIM;
        const float* b2  = mlp_b2 + (size_t)k * H_DIM;
        const float* l2b = lin2_b + (size_t)k * H_DIM;
        const float* ib  = intb   + (size_t)k * H_DIM;
        const short* w1h = w1t_h + (size_t)k * H_DIM * 64;
        const short* w1l = w1t_l + (size_t)k * H_DIM * 64;
        const short* w2h = w2t_h + (size_t)k * H_DIM * H_DIM;
        const short* w2l = w2t_l + (size_t)k * H_DIM * H_DIM;
        const short* l1h = l1t_h + (size_t)k * H_DIM * H_DIM;
        const short* l1l = l1t_l + (size_t)k * H_DIM * H_DIM;
        const short* l2h = l2t_h + (size_t)k * H_DIM * H_DIM;
        const short* l2l = l2t_l + (size_t)k * H_DIM * H_DIM;
        const short* ih  = int_h + (size_t)k * H_DIM * H_DIM;
        const short* il  = int_l + (size_t)k * H_DIM * H_DIM;

        // ttab = ssp(rtab @ w1 + b1)   [2048 x 600], K padded to 64
        gemm_mfma<true, true, false, false, true><<<dim3(GN, GMT), blk, 0, stream>>>(
            rtab_hi, rtab_lo, 64, w1h, w1l, 64, b1,
            nullptr, ttab_hi, ttab_lo, M_TAB, 64, H_DIM);
        // wtab = ttab @ w2 + b2        [2048 x 600]
        gemm_mfma<true, false, false, true, false><<<dim3(GN, GMT), blk, 0, stream>>>(
            ttab_hi, ttab_lo, H_DIM, w2h, w2l, H_DIM, b2,
            wtab, nullptr, nullptr, M_TAB, H_DIM, H_DIM);
        // y1 = h @ lin1                [10000 x 600]
        gemm_mfma<false, false, false, true, false><<<dim3(GN, GMN), blk, 0, stream>>>(
            h_hi, h_lo, H_DIM, l1h, l1l, H_DIM, nullptr,
            y1, nullptr, nullptr, N_ATOMS, H_DIM, H_DIM);
        // agg = CSR-gather(y1 * W(d) * C)  -> bf16 split
        gather_k<<<(N_ATOMS * QH + 255) / 256, blk, 0, stream>>>(
            y1, wtab, rowptr, esorted, agg_hi, agg_lo);
        // t = ssp(agg @ lin2 + b)      -> bf16 split (aliases y1)
        gemm_mfma<true, true, false, false, true><<<dim3(GN, GMN), blk, 0, stream>>>(
            agg_hi, agg_lo, H_DIM, l2h, l2l, H_DIM, l2b,
            nullptr, t_hi, t_lo, N_ATOMS, H_DIM, H_DIM);
        // h += t @ int_w + ib          (fp32 accumulate + refresh split)
        gemm_mfma<true, false, true, true, true><<<dim3(GN, GMN), blk, 0, stream>>>(
            t_hi, t_lo, H_DIM, ih, il, H_DIM, ib,
            h, h_hi, h_lo, N_ATOMS, H_DIM, H_DIM);
    }

    // mean pool per molecule, then out = pooled @ pool_w + pool_b
    hipMemsetAsync(sums, 0, (size_t)(B_MOLS * H_DIM + B_MOLS) * sizeof(float), stream);
    pool_sum_k<<<(N_ATOMS * QH + 255) / 256, blk, 0, stream>>>(h, batch, sums);
    cnt_k     <<<(N_ATOMS + 255) / 256,      blk, 0, stream>>>(batch, cnt);
    pool_div_k<<<(B_MOLS * H_DIM + 255) / 256, blk, 0, stream>>>(sums, cnt);
    gemm_k<true><<<dim3((H_DIM + BN - 1) / BN, (B_MOLS + BM - 1) / BM), blk, 0, stream>>>(
        sums, H_DIM, poolw, poolb, (float*)d_out, B_MOLS, H_DIM, H_DIM);
}